// Round 15
// baseline (648.948 us; speedup 1.0000x reference)
//
#include <hip/hip_runtime.h>
#include <hip/hip_bf16.h>
#include <hip/hip_cooperative_groups.h>

namespace cg = cooperative_groups;

// GIN forward: N=10000 nodes, E=80000 edges, per-node feature block [A=2][C=15][D=64]
// All inter-kernel tensors stored bf16; all reductions/BN/pool math in fp32.
// LESSONS LEDGER:
//  - R3/R11: do NOT fuse gather with GEMM (W-prologue can't amortize over 30 rows/node).
//  - R13: cooperative BCD fusion failed: grid==co-residency-limit boundary (1024==1024),
//    unchecked launch error -> stale stats. R15 retry: 750 blocks vs 768 limit, ws footprint
//    below R12's proven size (pp overlays bufQ), and a checked-fallback to the R12 path.
#define N_NODES   10000
#define N_EDGES   80000
#define R_TOTAL   300000
#define ELEMS     19200000   // R_TOTAL*64
#define NODE_F    1920       // 30*64 elements per node
#define N_TILES   18750      // R_TOTAL/16
#define PD_GRID   640        // fallback passD grid
#define GEMM_GRID 1024       // passA/passB grid
#define FB_GRID   750        // fused cooperative grid (3 blocks/CU -> limit 768)
#define FT_TILES  25         // tiles per fused block: 750*25 == 18750 exactly

typedef __attribute__((ext_vector_type(8))) short short8;   // 8 bf16
typedef __attribute__((ext_vector_type(4))) float f32x4;
typedef __attribute__((ext_vector_type(4))) unsigned int u32x4;
typedef __attribute__((ext_vector_type(2))) unsigned int u32x2;
typedef unsigned short ushort_t;

__device__ __forceinline__ unsigned short f2bf(float f) {
    unsigned u = __builtin_bit_cast(unsigned, f);
    unsigned r = u + 0x7fff + ((u >> 16) & 1);   // RNE
    return (unsigned short)(r >> 16);
}
__device__ __forceinline__ float lo_f(unsigned u) { return __builtin_bit_cast(float, u << 16); }
__device__ __forceinline__ float hi_f(unsigned u) { return __builtin_bit_cast(float, u & 0xffff0000u); }
__device__ __forceinline__ unsigned packbf(float lo, float hi) {
    return ((unsigned)f2bf(hi) << 16) | (unsigned)f2bf(lo);
}

__device__ __forceinline__ float coh_load(const float* p) {
    return __hip_atomic_load(p, __ATOMIC_RELAXED, __HIP_MEMORY_SCOPE_AGENT);
}

__device__ __forceinline__ void bn_coef(const float* __restrict__ ssum,
                                        const float* __restrict__ ssq,
                                        const float* __restrict__ g,
                                        const float* __restrict__ b, int j,
                                        float& sc, float& sh) {
    const float invM = 1.0f / (float)R_TOTAL;
    float m = ssum[j] * invM;
    float v = ssq[j] * invM - m * m;
    sc = g[j] * rsqrtf(v + 1e-5f);
    sh = b[j] - m * sc;
}

__device__ __forceinline__ void bn_coef_coh(const float* __restrict__ ssum,
                                            const float* __restrict__ ssq,
                                            const float* __restrict__ g,
                                            const float* __restrict__ b, int j,
                                            float& sc, float& sh) {
    const float invM = 1.0f / (float)R_TOTAL;
    float m = coh_load(&ssum[j]) * invM;
    float v = coh_load(&ssq[j]) * invM - m * m;
    sc = g[j] * rsqrtf(v + 1e-5f);
    sh = b[j] - m * sc;
}

// ---------------- transpose h[a][d][c][n] -> xb[n][a][c][d] (bf16), + pooled0 ----------------
__global__ __launch_bounds__(256) void k_transpose(const float* __restrict__ h,
                                                   ushort_t* __restrict__ xb,
                                                   float* __restrict__ pooled) {
    __shared__ float tile[64][65];    // [d][nn]
    int tn = blockIdx.x;              // n-tile 0..156
    int ac = blockIdx.y;              // 0..29
    int a = ac / 15, c = ac % 15;
    int t = threadIdx.x;
    int n0 = tn * 64;

    int r = t >> 4, g = t & 15;
    int nbase = n0 + 4 * g;
    const float* hp = h + (size_t)a * 9600000 + (size_t)c * 10000;
#pragma unroll
    for (int it = 0; it < 4; it++) {
        int d = it * 16 + r;
        const float* p = hp + (size_t)d * 150000 + nbase;
        float4 v;
        if (nbase + 3 < N_NODES) {
            v = *(const float4*)p;
        } else {
            v.x = (nbase + 0 < N_NODES) ? p[0] : 0.f;
            v.y = (nbase + 1 < N_NODES) ? p[1] : 0.f;
            v.z = (nbase + 2 < N_NODES) ? p[2] : 0.f;
            v.w = (nbase + 3 < N_NODES) ? p[3] : 0.f;
        }
        tile[d][4 * g + 0] = v.x;
        tile[d][4 * g + 1] = v.y;
        tile[d][4 * g + 2] = v.z;
        tile[d][4 * g + 3] = v.w;
    }
    __syncthreads();

    int nn = t >> 2, dg = (t & 3) * 16;
    int n = n0 + nn;
    if (n < N_NODES) {
        u32x4 oA, oB;
#pragma unroll
        for (int q = 0; q < 4; q++) {
            oA[q] = packbf(tile[dg + 2 * q][nn],     tile[dg + 2 * q + 1][nn]);
            oB[q] = packbf(tile[dg + 8 + 2 * q][nn], tile[dg + 8 + 2 * q + 1][nn]);
        }
        ushort_t* dst = xb + ((size_t)(n * 30 + ac)) * 64 + dg;
        *(u32x4*)dst = oA;
        *(u32x4*)(dst + 8) = oB;
    }

    if (t < 64) {
        float s = 0.f;
        int lim = min(64, N_NODES - n0);
        for (int j = 0; j < lim; j++) s += tile[t][j];
        atomicAdd(&pooled[ac * 64 + t], s);
    }
}

// ---------------- CSR build: degree -> scan -> fill ----------------
__global__ void k_deg(const int* __restrict__ dst, int* __restrict__ deg) {
    int e = blockIdx.x * 256 + threadIdx.x;
    if (e < N_EDGES) atomicAdd(&deg[dst[e]], 1);
}

__global__ __launch_bounds__(256) void k_scan(const int* __restrict__ deg,
                                              int* __restrict__ off,
                                              int* __restrict__ cursor) {
    __shared__ int buf[256];
    int t = threadIdx.x;
    int c0 = t * 40;                 // 256*40 = 10240 >= 10000
    int local[40];
    int s = 0;
    for (int i = 0; i < 40; i++) {
        int idx = c0 + i;
        int d = (idx < N_NODES) ? deg[idx] : 0;
        local[i] = d;
        s += d;
    }
    buf[t] = s;
    __syncthreads();
    for (int st = 1; st < 256; st <<= 1) {
        int v = (t >= st) ? buf[t - st] : 0;
        __syncthreads();
        buf[t] += v;
        __syncthreads();
    }
    int run = buf[t] - s;
    for (int i = 0; i < 40; i++) {
        int idx = c0 + i;
        if (idx < N_NODES) {
            off[idx] = run;
            cursor[idx] = run;
            run += local[i];
        }
    }
    if (t == 255) off[N_NODES] = buf[255];
}

__global__ void k_fill(const int* __restrict__ src, const int* __restrict__ dst,
                       int* __restrict__ cursor, int* __restrict__ csr) {
    int e = blockIdx.x * 256 + threadIdx.x;
    if (e < N_EDGES) {
        int p = atomicAdd(&cursor[dst[e]], 1);
        csr[p] = src[e];
    }
}

// ---------------- gather (bf16): aggb[n] = sum_{e in in(n)} xb[csr_src[e]] ----------------
__global__ __launch_bounds__(256) void k_gather(const ushort_t* __restrict__ xb,
                                                ushort_t* __restrict__ aggb,
                                                const int* __restrict__ off,
                                                const int* __restrict__ csr) {
    __shared__ int eds[256];
    int n = blockIdx.x;
    int t = threadIdx.x;
    bool act = t < 240;
    int e0 = off[n], e1 = off[n + 1];
    float acc[8] = {0.f, 0.f, 0.f, 0.f, 0.f, 0.f, 0.f, 0.f};
    for (int base = e0; base < e1; base += 256) {
        int cnt = min(256, e1 - base);
        __syncthreads();
        if (t < cnt) eds[t] = csr[base + t];
        __syncthreads();
        if (act) {
            int i = 0;
            for (; i + 8 <= cnt; i += 8) {
                u32x4 v0 = *(const u32x4*)(xb + (size_t)eds[i + 0] * NODE_F + t * 8);
                u32x4 v1 = *(const u32x4*)(xb + (size_t)eds[i + 1] * NODE_F + t * 8);
                u32x4 v2 = *(const u32x4*)(xb + (size_t)eds[i + 2] * NODE_F + t * 8);
                u32x4 v3 = *(const u32x4*)(xb + (size_t)eds[i + 3] * NODE_F + t * 8);
                u32x4 v4 = *(const u32x4*)(xb + (size_t)eds[i + 4] * NODE_F + t * 8);
                u32x4 v5 = *(const u32x4*)(xb + (size_t)eds[i + 5] * NODE_F + t * 8);
                u32x4 v6 = *(const u32x4*)(xb + (size_t)eds[i + 6] * NODE_F + t * 8);
                u32x4 v7 = *(const u32x4*)(xb + (size_t)eds[i + 7] * NODE_F + t * 8);
#pragma unroll
                for (int q = 0; q < 4; q++) {
                    acc[2 * q]     += (lo_f(v0[q]) + lo_f(v1[q])) + (lo_f(v2[q]) + lo_f(v3[q]))
                                    + (lo_f(v4[q]) + lo_f(v5[q])) + (lo_f(v6[q]) + lo_f(v7[q]));
                    acc[2 * q + 1] += (hi_f(v0[q]) + hi_f(v1[q])) + (hi_f(v2[q]) + hi_f(v3[q]))
                                    + (hi_f(v4[q]) + hi_f(v5[q])) + (hi_f(v6[q]) + hi_f(v7[q]));
                }
            }
            for (; i + 4 <= cnt; i += 4) {
                u32x4 v0 = *(const u32x4*)(xb + (size_t)eds[i + 0] * NODE_F + t * 8);
                u32x4 v1 = *(const u32x4*)(xb + (size_t)eds[i + 1] * NODE_F + t * 8);
                u32x4 v2 = *(const u32x4*)(xb + (size_t)eds[i + 2] * NODE_F + t * 8);
                u32x4 v3 = *(const u32x4*)(xb + (size_t)eds[i + 3] * NODE_F + t * 8);
#pragma unroll
                for (int q = 0; q < 4; q++) {
                    acc[2 * q]     += (lo_f(v0[q]) + lo_f(v1[q])) + (lo_f(v2[q]) + lo_f(v3[q]));
                    acc[2 * q + 1] += (hi_f(v0[q]) + hi_f(v1[q])) + (hi_f(v2[q]) + hi_f(v3[q]));
                }
            }
            for (; i < cnt; i++) {
                u32x4 v = *(const u32x4*)(xb + (size_t)eds[i] * NODE_F + t * 8);
#pragma unroll
                for (int q = 0; q < 4; q++) {
                    acc[2 * q]     += lo_f(v[q]);
                    acc[2 * q + 1] += hi_f(v[q]);
                }
            }
        }
    }
    if (act) {
        u32x4 o;
#pragma unroll
        for (int q = 0; q < 4; q++) o[q] = packbf(acc[2 * q], acc[2 * q + 1]);
        *(u32x4*)(aggb + (size_t)n * NODE_F + t * 8) = o;
    }
}

// ---------------- passA (MFMA): to = ((1+eps)*x + agg) @ W0 + b0 ; stats(to) ----------------
__global__ __launch_bounds__(256) void k_passA(const ushort_t* __restrict__ xb,
                                               const ushort_t* __restrict__ aggb,
                                               ushort_t* __restrict__ to,
                                               const float* __restrict__ W,
                                               const float* __restrict__ bias,
                                               const float* __restrict__ epsp, int l,
                                               float* __restrict__ ssum, float* __restrict__ ssq) {
    int tid = threadIdx.x;
    int lane = tid & 63, wid = tid >> 6;
    int m = lane & 15, kg = lane >> 4;

    short8 bfr[2][4];                 // [kstep][nt] ; col = 4m+nt
#pragma unroll
    for (int s = 0; s < 2; s++)
#pragma unroll
        for (int nt = 0; nt < 4; nt++) {
            short8 v;
#pragma unroll
            for (int j = 0; j < 8; j++)
                v[j] = (short)f2bf(W[(s * 32 + kg * 8 + j) * 64 + 4 * m + nt]);
            bfr[s][nt] = v;
        }
    float bcol[4];
#pragma unroll
    for (int nt = 0; nt < 4; nt++) bcol[nt] = bias[4 * m + nt];
    float e1 = 1.0f + epsp[l];

    float s0a[4] = {0.f, 0.f, 0.f, 0.f}, s1a[4] = {0.f, 0.f, 0.f, 0.f};

    for (int tile = blockIdx.x * 4 + wid; tile < N_TILES; tile += gridDim.x * 4) {
        size_t row0 = (size_t)tile * 16;
        const u32x4* xr = (const u32x4*)(xb + (row0 + m) * 64);
        const u32x4* ar = (const u32x4*)(aggb + (row0 + m) * 64);
        short8 afr[2];
#pragma unroll
        for (int s = 0; s < 2; s++) {
            u32x4 xv = xr[s * 4 + kg];
            u32x4 av = ar[s * 4 + kg];
            u32x4 zv;
#pragma unroll
            for (int q = 0; q < 4; q++) {
                float zl = fmaf(e1, lo_f(xv[q]), lo_f(av[q]));
                float zh = fmaf(e1, hi_f(xv[q]), hi_f(av[q]));
                zv[q] = packbf(zl, zh);
            }
            afr[s] = __builtin_bit_cast(short8, zv);
        }
        f32x4 acc0 = {0,0,0,0}, acc1 = {0,0,0,0}, acc2 = {0,0,0,0}, acc3 = {0,0,0,0};
#pragma unroll
        for (int s = 0; s < 2; s++) {
            acc0 = __builtin_amdgcn_mfma_f32_16x16x32_bf16(afr[s], bfr[s][0], acc0, 0, 0, 0);
            acc1 = __builtin_amdgcn_mfma_f32_16x16x32_bf16(afr[s], bfr[s][1], acc1, 0, 0, 0);
            acc2 = __builtin_amdgcn_mfma_f32_16x16x32_bf16(afr[s], bfr[s][2], acc2, 0, 0, 0);
            acc3 = __builtin_amdgcn_mfma_f32_16x16x32_bf16(afr[s], bfr[s][3], acc3, 0, 0, 0);
        }
        ushort_t* tw = to + (row0 + kg * 4) * 64 + 4 * m;
#pragma unroll
        for (int r = 0; r < 4; r++) {
            float v0 = acc0[r] + bcol[0];
            float v1 = acc1[r] + bcol[1];
            float v2 = acc2[r] + bcol[2];
            float v3 = acc3[r] + bcol[3];
            u32x2 pk;
            pk[0] = packbf(v0, v1);
            pk[1] = packbf(v2, v3);
            *(u32x2*)(tw + (size_t)r * 64) = pk;
            s0a[0] += v0; s1a[0] += v0 * v0;
            s0a[1] += v1; s1a[1] += v1 * v1;
            s0a[2] += v2; s1a[2] += v2 * v2;
            s0a[3] += v3; s1a[3] += v3 * v3;
        }
    }
    __shared__ float shs0[64], shs1[64];
    if (tid < 64) { shs0[tid] = 0.f; shs1[tid] = 0.f; }
    __syncthreads();
#pragma unroll
    for (int nt = 0; nt < 4; nt++) {
        atomicAdd(&shs0[4 * m + nt], s0a[nt]);
        atomicAdd(&shs1[4 * m + nt], s1a[nt]);
    }
    __syncthreads();
    if (tid < 64) {
        atomicAdd(&ssum[tid], shs0[tid]);
        atomicAdd(&ssq[tid], shs1[tid]);
    }
}

// ---------------- fused passB + statsC + passD (cooperative, checked launch) ----------------
// 750 blocks x 25 tiles; t3 lives only in LDS (51.7KB -> 3 blocks/CU, limit 768 >= 750).
__global__ __launch_bounds__(256, 3) void k_fusedBCD(
        const ushort_t* __restrict__ t1buf,
        ushort_t* __restrict__ xb,
        const float* __restrict__ W,
        const float* __restrict__ bias,
        const float* __restrict__ ssum0, const float* __restrict__ ssq0,
        const float* __restrict__ g0, const float* __restrict__ be0,
        float* __restrict__ ssum1, float* __restrict__ ssq1,
        const float* __restrict__ ga, const float* __restrict__ ba,
        float* __restrict__ ssum2, float* __restrict__ ssq2,
        const float* __restrict__ go, const float* __restrict__ bo,
        float* __restrict__ pp, int writeX) {
    __shared__ ushort_t t3l[FT_TILES * 1024];   // 25 tiles x [16][64] bf16 = 51200 B
    __shared__ float shs0[64], shs1[64];
    cg::grid_group grid = cg::this_grid();

    int t = threadIdx.x;
    int lane = t & 63, w = t >> 6;
    int m = lane & 15, kg = lane >> 4;
    int bid = blockIdx.x;
    int t0 = bid * FT_TILES;
    int c8 = t & 7;

    float sc_a[8], sh_a[8];

    // ======== phase 1: t3 = relu(bn0(t1)) @ W1 + b1 -> LDS; stats(t3) ========
    {
        short8 bfr[2][4];             // col = 4m+nt
#pragma unroll
        for (int s = 0; s < 2; s++)
#pragma unroll
            for (int ntc = 0; ntc < 4; ntc++) {
                short8 v;
#pragma unroll
                for (int j = 0; j < 8; j++)
                    v[j] = (short)f2bf(W[(s * 32 + kg * 8 + j) * 64 + 4 * m + ntc]);
                bfr[s][ntc] = v;
            }
        float bcol[4];
#pragma unroll
        for (int ntc = 0; ntc < 4; ntc++) bcol[ntc] = bias[4 * m + ntc];
        float scv[2][8], shv[2][8];
#pragma unroll
        for (int s = 0; s < 2; s++)
#pragma unroll
            for (int j = 0; j < 8; j++)
                bn_coef(ssum0, ssq0, g0, be0, s * 32 + kg * 8 + j, scv[s][j], shv[s][j]);

        if (t < 64) { shs0[t] = 0.f; shs1[t] = 0.f; }
        __syncthreads();

        float s0a[4] = {0.f, 0.f, 0.f, 0.f}, s1a[4] = {0.f, 0.f, 0.f, 0.f};
        for (int ti = w; ti < FT_TILES; ti += 4) {
            size_t row0 = (size_t)(t0 + ti) * 16;
            const u32x4* tr = (const u32x4*)(t1buf + (row0 + m) * 64);
            short8 afr[2];
#pragma unroll
            for (int s = 0; s < 2; s++) {
                u32x4 tv = tr[s * 4 + kg];
                u32x4 zv;
#pragma unroll
                for (int q = 0; q < 4; q++) {
                    float zl_ = fmaxf(fmaf(lo_f(tv[q]), scv[s][2 * q],     shv[s][2 * q]),     0.f);
                    float zh_ = fmaxf(fmaf(hi_f(tv[q]), scv[s][2 * q + 1], shv[s][2 * q + 1]), 0.f);
                    zv[q] = packbf(zl_, zh_);
                }
                afr[s] = __builtin_bit_cast(short8, zv);
            }
            f32x4 acc0 = {0,0,0,0}, acc1 = {0,0,0,0}, acc2 = {0,0,0,0}, acc3 = {0,0,0,0};
#pragma unroll
            for (int s = 0; s < 2; s++) {
                acc0 = __builtin_amdgcn_mfma_f32_16x16x32_bf16(afr[s], bfr[s][0], acc0, 0, 0, 0);
                acc1 = __builtin_amdgcn_mfma_f32_16x16x32_bf16(afr[s], bfr[s][1], acc1, 0, 0, 0);
                acc2 = __builtin_amdgcn_mfma_f32_16x16x32_bf16(afr[s], bfr[s][2], acc2, 0, 0, 0);
                acc3 = __builtin_amdgcn_mfma_f32_16x16x32_bf16(afr[s], bfr[s][3], acc3, 0, 0, 0);
            }
            ushort_t* tw = t3l + ((size_t)ti * 16 + kg * 4) * 64 + 4 * m;
#pragma unroll
            for (int r = 0; r < 4; r++) {
                float v0 = acc0[r] + bcol[0];
                float v1 = acc1[r] + bcol[1];
                float v2 = acc2[r] + bcol[2];
                float v3 = acc3[r] + bcol[3];
                u32x2 pk;
                pk[0] = packbf(v0, v1);
                pk[1] = packbf(v2, v3);
                *(u32x2*)(tw + (size_t)r * 64) = pk;
                s0a[0] += v0; s1a[0] += v0 * v0;
                s0a[1] += v1; s1a[1] += v1 * v1;
                s0a[2] += v2; s1a[2] += v2 * v2;
                s0a[3] += v3; s1a[3] += v3 * v3;
            }
        }
#pragma unroll
        for (int ntc = 0; ntc < 4; ntc++) {
            atomicAdd(&shs0[4 * m + ntc], s0a[ntc]);
            atomicAdd(&shs1[4 * m + ntc], s1a[ntc]);
        }
        __syncthreads();
        if (t < 64) {
            atomicAdd(&ssum1[t], shs0[t]);
            atomicAdd(&ssq1[t], shs1[t]);
        }
    }
    grid.sync();

    // ======== phase 2: stats of u = relu(bn_a(t3)) from LDS ========
#pragma unroll
    for (int j = 0; j < 8; j++)
        bn_coef_coh(ssum1, ssq1, ga, ba, c8 * 8 + j, sc_a[j], sh_a[j]);
    {
        if (t < 64) { shs0[t] = 0.f; shs1[t] = 0.f; }
        __syncthreads();
        float s0[8] = {0,0,0,0,0,0,0,0}, s1[8] = {0,0,0,0,0,0,0,0};
        const int nchunks = FT_TILES * 128;     // 16B chunks; idx % 8 == t % 8 -> c8 fixed
        for (int idx = t; idx < nchunks; idx += 256) {
            u32x4 v = *(const u32x4*)(t3l + (size_t)idx * 8);
#pragma unroll
            for (int q = 0; q < 4; q++) {
                float e;
                e = fmaxf(fmaf(lo_f(v[q]), sc_a[2 * q],     sh_a[2 * q]),     0.f);
                s0[2 * q] += e;     s1[2 * q] += e * e;
                e = fmaxf(fmaf(hi_f(v[q]), sc_a[2 * q + 1], sh_a[2 * q + 1]), 0.f);
                s0[2 * q + 1] += e; s1[2 * q + 1] += e * e;
            }
        }
#pragma unroll
        for (int j = 0; j < 8; j++) {
            atomicAdd(&shs0[c8 * 8 + j], s0[j]);
            atomicAdd(&shs1[c8 * 8 + j], s1[j]);
        }
        __syncthreads();
        if (t < 64) {
            atomicAdd(&ssum2[t], shs0[t]);
            atomicAdd(&ssq2[t], shs1[t]);
        }
    }
    grid.sync();

    // ======== phase 3: y = relu(bn_o(relu(bn_a(t3)))); write xb + pool partials ========
    if (t < 240) {
        int ac = t >> 3;              // 0..29
        float sc_o[8], sh_o[8];
#pragma unroll
        for (int j = 0; j < 8; j++)
            bn_coef_coh(ssum2, ssq2, go, bo, c8 * 8 + j, sc_o[j], sh_o[j]);
        float pool[8] = {0,0,0,0,0,0,0,0};
        int r0 = t0 * 16;             // 400 rows per block
        int rend = r0 + FT_TILES * 16;
        int rfirst = r0 + ((ac - (r0 % 30)) % 30 + 30) % 30;
        for (int r = rfirst; r < rend; r += 30) {
            int lr = r - r0;
            u32x4 v = *(const u32x4*)(t3l + (size_t)lr * 64 + c8 * 8);
            u32x4 o;
#pragma unroll
            for (int q = 0; q < 4; q++) {
                float ul = fmaxf(fmaf(lo_f(v[q]), sc_a[2 * q],     sh_a[2 * q]),     0.f);
                float uh = fmaxf(fmaf(hi_f(v[q]), sc_a[2 * q + 1], sh_a[2 * q + 1]), 0.f);
                float yl = fmaxf(fmaf(ul, sc_o[2 * q],     sh_o[2 * q]),     0.f);
                float yh = fmaxf(fmaf(uh, sc_o[2 * q + 1], sh_o[2 * q + 1]), 0.f);
                pool[2 * q] += yl;
                pool[2 * q + 1] += yh;
                o[q] = packbf(yl, yh);
            }
            if (writeX) *(u32x4*)(xb + (size_t)r * 64 + c8 * 8) = o;
        }
        float4* pb = (float4*)(pp + (size_t)bid * NODE_F + ac * 64 + c8 * 8);
        pb[0] = make_float4(pool[0], pool[1], pool[2], pool[3]);
        pb[1] = make_float4(pool[4], pool[5], pool[6], pool[7]);
    }
}

// ---------------- FALLBACK: passB (MFMA) ----------------
__global__ __launch_bounds__(256) void k_passB(const ushort_t* __restrict__ ti,
                                               ushort_t* __restrict__ to,
                                               const float* __restrict__ W,
                                               const float* __restrict__ bias,
                                               const float* __restrict__ ssum0,
                                               const float* __restrict__ ssq0,
                                               const float* __restrict__ g0,
                                               const float* __restrict__ be0,
                                               float* __restrict__ ssum, float* __restrict__ ssq) {
    int tid = threadIdx.x;
    int lane = tid & 63, wid = tid >> 6;
    int m = lane & 15, kg = lane >> 4;

    short8 bfr[2][4];
#pragma unroll
    for (int s = 0; s < 2; s++)
#pragma unroll
        for (int nt = 0; nt < 4; nt++) {
            short8 v;
#pragma unroll
            for (int j = 0; j < 8; j++)
                v[j] = (short)f2bf(W[(s * 32 + kg * 8 + j) * 64 + 4 * m + nt]);
            bfr[s][nt] = v;
        }
    float bcol[4];
#pragma unroll
    for (int nt = 0; nt < 4; nt++) bcol[nt] = bias[4 * m + nt];
    float scv[2][8], shv[2][8];
#pragma unroll
    for (int s = 0; s < 2; s++)
#pragma unroll
        for (int j = 0; j < 8; j++)
            bn_coef(ssum0, ssq0, g0, be0, s * 32 + kg * 8 + j, scv[s][j], shv[s][j]);

    float s0a[4] = {0.f, 0.f, 0.f, 0.f}, s1a[4] = {0.f, 0.f, 0.f, 0.f};

    for (int tile = blockIdx.x * 4 + wid; tile < N_TILES; tile += gridDim.x * 4) {
        size_t row0 = (size_t)tile * 16;
        const u32x4* tr = (const u32x4*)(ti + (row0 + m) * 64);
        short8 afr[2];
#pragma unroll
        for (int s = 0; s < 2; s++) {
            u32x4 tv = tr[s * 4 + kg];
            u32x4 zv;
#pragma unroll
            for (int q = 0; q < 4; q++) {
                float zl_ = fmaxf(fmaf(lo_f(tv[q]), scv[s][2 * q],     shv[s][2 * q]),     0.f);
                float zh_ = fmaxf(fmaf(hi_f(tv[q]), scv[s][2 * q + 1], shv[s][2 * q + 1]), 0.f);
                zv[q] = packbf(zl_, zh_);
            }
            afr[s] = __builtin_bit_cast(short8, zv);
        }
        f32x4 acc0 = {0,0,0,0}, acc1 = {0,0,0,0}, acc2 = {0,0,0,0}, acc3 = {0,0,0,0};
#pragma unroll
        for (int s = 0; s < 2; s++) {
            acc0 = __builtin_amdgcn_mfma_f32_16x16x32_bf16(afr[s], bfr[s][0], acc0, 0, 0, 0);
            acc1 = __builtin_amdgcn_mfma_f32_16x16x32_bf16(afr[s], bfr[s][1], acc1, 0, 0, 0);
            acc2 = __builtin_amdgcn_mfma_f32_16x16x32_bf16(afr[s], bfr[s][2], acc2, 0, 0, 0);
            acc3 = __builtin_amdgcn_mfma_f32_16x16x32_bf16(afr[s], bfr[s][3], acc3, 0, 0, 0);
        }
        ushort_t* tw = to + (row0 + kg * 4) * 64 + 4 * m;
#pragma unroll
        for (int r = 0; r < 4; r++) {
            float v0 = acc0[r] + bcol[0];
            float v1 = acc1[r] + bcol[1];
            float v2 = acc2[r] + bcol[2];
            float v3 = acc3[r] + bcol[3];
            u32x2 pk;
            pk[0] = packbf(v0, v1);
            pk[1] = packbf(v2, v3);
            *(u32x2*)(tw + (size_t)r * 64) = pk;
            s0a[0] += v0; s1a[0] += v0 * v0;
            s0a[1] += v1; s1a[1] += v1 * v1;
            s0a[2] += v2; s1a[2] += v2 * v2;
            s0a[3] += v3; s1a[3] += v3 * v3;
        }
    }
    __shared__ float shs0[64], shs1[64];
    if (tid < 64) { shs0[tid] = 0.f; shs1[tid] = 0.f; }
    __syncthreads();
#pragma unroll
    for (int nt = 0; nt < 4; nt++) {
        atomicAdd(&shs0[4 * m + nt], s0a[nt]);
        atomicAdd(&shs1[4 * m + nt], s1a[nt]);
    }
    __syncthreads();
    if (tid < 64) {
        atomicAdd(&ssum[tid], shs0[tid]);
        atomicAdd(&ssq[tid], shs1[tid]);
    }
}

// ---------------- FALLBACK: statsC ----------------
__global__ __launch_bounds__(256) void k_statsC(const ushort_t* __restrict__ tb,
                                                const float* __restrict__ ssum1,
                                                const float* __restrict__ ssq1,
                                                const float* __restrict__ ga,
                                                const float* __restrict__ ba,
                                                float* __restrict__ ssum2,
                                                float* __restrict__ ssq2) {
    __shared__ float shs0[64], shs1[64];
    int tid = threadIdx.x;
    if (tid < 64) { shs0[tid] = 0.f; shs1[tid] = 0.f; }
    __syncthreads();
    int ch0 = (tid & 7) * 8;
    float sc[8], sh[8];
#pragma unroll
    for (int j = 0; j < 8; j++) bn_coef(ssum1, ssq1, ga, ba, ch0 + j, sc[j], sh[j]);
    float s0[8] = {0,0,0,0,0,0,0,0}, s1[8] = {0,0,0,0,0,0,0,0};
    const u32x4* t4 = (const u32x4*)tb;
    const int total = ELEMS / 8;
    int stride = gridDim.x * 256;
    for (int i = blockIdx.x * 256 + tid; i < total; i += stride) {
        u32x4 v = t4[i];
#pragma unroll
        for (int q = 0; q < 4; q++) {
            float e;
            e = fmaxf(fmaf(lo_f(v[q]), sc[2 * q],     sh[2 * q]),     0.f);
            s0[2 * q] += e;     s1[2 * q] += e * e;
            e = fmaxf(fmaf(hi_f(v[q]), sc[2 * q + 1], sh[2 * q + 1]), 0.f);
            s0[2 * q + 1] += e; s1[2 * q + 1] += e * e;
        }
    }
#pragma unroll
    for (int j = 0; j < 8; j++) {
        atomicAdd(&shs0[ch0 + j], s0[j]);
        atomicAdd(&shs1[ch0 + j], s1[j]);
    }
    __syncthreads();
    if (tid < 64) {
        atomicAdd(&ssum2[tid], shs0[tid]);
        atomicAdd(&ssq2[tid], shs1[tid]);
    }
}

// ---------------- FALLBACK: passD ----------------
__global__ __launch_bounds__(256) void k_passD(const ushort_t* __restrict__ tb,
                                               ushort_t* __restrict__ xb,
                                               const float* __restrict__ ssum1,
                                               const float* __restrict__ ssq1,
                                               const float* __restrict__ ga,
                                               const float* __restrict__ ba,
                                               const float* __restrict__ ssum2,
                                               const float* __restrict__ ssq2,
                                               const float* __restrict__ go,
                                               const float* __restrict__ bo,
                                               float* __restrict__ pp,
                                               int writeX) {
    int t = threadIdx.x;
    bool act = t < 240;
    int ch0 = (t & 7) * 8;
    float sc1[8], sh1[8], sc2[8], sh2[8];
#pragma unroll
    for (int j = 0; j < 8; j++) {
        bn_coef(ssum1, ssq1, ga, ba, ch0 + j, sc1[j], sh1[j]);
        bn_coef(ssum2, ssq2, go, bo, ch0 + j, sc2[j], sh2[j]);
    }
    float pool[8] = {0,0,0,0,0,0,0,0};
    if (act) {
        for (int n = blockIdx.x; n < N_NODES; n += gridDim.x) {
            const u32x4* tr = (const u32x4*)(tb + (size_t)n * NODE_F);
            u32x4 v = tr[t];
            u32x4 o;
#pragma unroll
            for (int q = 0; q < 4; q++) {
                float el = fmaxf(fmaf(fmaxf(fmaf(lo_f(v[q]), sc1[2 * q], sh1[2 * q]), 0.f),
                                      sc2[2 * q], sh2[2 * q]), 0.f);
                float eh = fmaxf(fmaf(fmaxf(fmaf(hi_f(v[q]), sc1[2 * q + 1], sh1[2 * q + 1]), 0.f),
                                      sc2[2 * q + 1], sh2[2 * q + 1]), 0.f);
                pool[2 * q] += el;
                pool[2 * q + 1] += eh;
                o[q] = packbf(el, eh);
            }
            if (writeX) *(u32x4*)(xb + (size_t)n * NODE_F + t * 8) = o;
        }
        float4* pb = (float4*)(pp + (size_t)blockIdx.x * NODE_F + t * 8);
        pb[0] = make_float4(pool[0], pool[1], pool[2], pool[3]);
        pb[1] = make_float4(pool[4], pool[5], pool[6], pool[7]);
    }
}

// ---------------- redpool (generic row count): grid (8, 16) ----------------
__global__ __launch_bounds__(256) void k_redpool(const float* __restrict__ pp,
                                                 float* __restrict__ dstp, int nrows) {
    int ch = blockIdx.x * 256 + threadIdx.x;
    if (ch >= NODE_F) return;
    float a = 0.f;
    for (int b = blockIdx.y; b < nrows; b += 16)
        a += pp[(size_t)b * NODE_F + ch];
    atomicAdd(&dstp[ch], a);
}

// ---------------- final readout: score + fc -> out[2] ----------------
__global__ void k_final(const float* __restrict__ pooled,   // [3][1920]
                        const float* __restrict__ Wp,       // [3][64][10]
                        const float* __restrict__ bp,       // [3][10]
                        const float* __restrict__ Wfc,      // [15][10]
                        const float* __restrict__ bfc, float* __restrict__ out) {
    __shared__ float oa[2];
    int t = threadIdx.x;
    if (t < 2) oa[t] = 0.f;
    __syncthreads();
    if (t < 300) {
        int a = t / 150, rem = t % 150, c = rem / 10, hh = rem % 10;
        int ac = a * 15 + c;
        float sc_sum = 0.f;
        for (int i = 0; i < 3; i++) {
            float s = bp[i * 10 + hh];
            const float* pp = pooled + i * NODE_F + ac * 64;
            const float* wp = Wp + i * 640 + hh;
            for (int d = 0; d < 64; d++) s += pp[d] * wp[d * 10];
            sc_sum += s;
        }
        atomicAdd(&oa[a], sc_sum * Wfc[c * 10 + hh]);
    }
    __syncthreads();
    if (t < 2) out[t] = oa[t] + bfc[0];
}

extern "C" void kernel_launch(void* const* d_in, const int* in_sizes, int n_in,
                              void* d_out, int out_size, void* d_ws, size_t ws_size,
                              hipStream_t stream) {
    const float* h   = (const float*)d_in[0];
    const float* eps = (const float*)d_in[1];
    const float* W0  = (const float*)d_in[2];
    const float* b0  = (const float*)d_in[3];
    const float* g0  = (const float*)d_in[4];
    const float* be0 = (const float*)d_in[5];
    const float* W1  = (const float*)d_in[6];
    const float* b1  = (const float*)d_in[7];
    const float* ga  = (const float*)d_in[8];
    const float* ba  = (const float*)d_in[9];
    const float* go  = (const float*)d_in[10];
    const float* bo  = (const float*)d_in[11];
    const float* Wp  = (const float*)d_in[12];
    const float* bp  = (const float*)d_in[13];
    const float* Wfc = (const float*)d_in[14];
    const float* bfc = (const float*)d_in[15];
    const int*   src = (const int*)d_in[16];
    const int*   dst = (const int*)d_in[17];
    float* out = (float*)d_out;

    ushort_t* xb   = (ushort_t*)d_ws;            // [ELEMS] bf16 (node features)
    ushort_t* bufP = xb + ELEMS;                 // [ELEMS] bf16 (agg / t3)
    ushort_t* bufQ = bufP + ELEMS;               // [ELEMS] bf16 (t1; pool partials overlay)
    float* small   = (float*)(bufQ + ELEMS);
    float* bn = small;                           // 6 x [sum64|sq64] padded to 256
    float* pooled = small + 6 * 256;             // [3][1920]
    int* ideg = (int*)(pooled + 3 * NODE_F);     // [10000]
    int* ioff = ideg + N_NODES;                  // [10001]
    int* icur = ioff + N_NODES + 1;              // [10000]
    int* icsr = icur + N_NODES;                  // [80000]
    float* pp_l = (float*)bufQ;                  // overlay: t1 dead before pp writes

    hipMemsetAsync(small, 0,
                   (6 * 256 + 3 * NODE_F) * sizeof(float) + N_NODES * sizeof(int), stream);

    k_deg<<<(N_EDGES + 255) / 256, 256, 0, stream>>>(dst, ideg);
    k_scan<<<1, 256, 0, stream>>>(ideg, ioff, icur);
    k_fill<<<(N_EDGES + 255) / 256, 256, 0, stream>>>(src, dst, icur, icsr);

    k_transpose<<<dim3(157, 30), 256, 0, stream>>>(h, xb, pooled);

    for (int l = 0; l < 2; l++) {
        float* s0s = bn + l * 3 * 256;
        float* s1s = s0s + 256;
        float* s2s = s1s + 256;
        k_gather<<<N_NODES, 256, 0, stream>>>(xb, bufP, ioff, icsr);
        k_passA<<<GEMM_GRID, 256, 0, stream>>>(xb, bufP, bufQ,
                                               W0 + l * 4096, b0 + l * 64, eps, l,
                                               s0s, s0s + 64);
        // fused passB+statsC+passD (cooperative, checked) with R12-path fallback
        int nrows;
        {
            const ushort_t* t1p = bufQ;
            ushort_t* xbp = xb;
            const float* Wp1 = W1 + l * 4096;
            const float* bp1 = b1 + l * 64;
            const float* ss0 = s0s;         const float* sq0 = s0s + 64;
            const float* g0p = g0 + l * 64; const float* be0p = be0 + l * 64;
            float* ss1 = s1s;               float* sq1 = s1s + 64;
            const float* gap = ga + l * 64; const float* bap = ba + l * 64;
            float* ss2 = s2s;               float* sq2 = s2s + 64;
            const float* gop = go + l * 64; const float* bop = bo + l * 64;
            float* ppl = pp_l;
            int wx = (l == 0) ? 1 : 0;
            void* args[] = {
                (void*)&t1p, (void*)&xbp, (void*)&Wp1, (void*)&bp1,
                (void*)&ss0, (void*)&sq0, (void*)&g0p, (void*)&be0p,
                (void*)&ss1, (void*)&sq1, (void*)&gap, (void*)&bap,
                (void*)&ss2, (void*)&sq2, (void*)&gop, (void*)&bop,
                (void*)&ppl, (void*)&wx
            };
            hipError_t ce = hipLaunchCooperativeKernel((const void*)k_fusedBCD,
                                                       dim3(FB_GRID), dim3(256),
                                                       args, 0, stream);
            if (ce == hipSuccess) {
                nrows = FB_GRID;
            } else {
                // fallback: proven R12 three-kernel path (bufP <- t3)
                k_passB<<<GEMM_GRID, 256, 0, stream>>>(bufQ, bufP, Wp1, bp1,
                                                       ss0, sq0, g0p, be0p, ss1, sq1);
                k_statsC<<<1024, 256, 0, stream>>>(bufP, ss1, sq1, gap, bap, ss2, sq2);
                k_passD<<<PD_GRID, 256, 0, stream>>>(bufP, xb, ss1, sq1, gap, bap,
                                                     ss2, sq2, gop, bop, pp_l, wx);
                nrows = PD_GRID;
            }
        }
        k_redpool<<<dim3(8, 16), 256, 0, stream>>>(pp_l, pooled + (l + 1) * NODE_F, nrows);
    }
    k_final<<<1, 320, 0, stream>>>(pooled, Wp, bp, Wfc, bfc, out);
}

// Round 16
// 432.415 us; speedup vs baseline: 1.5008x; 1.5008x over previous
//
#include <hip/hip_runtime.h>
#include <hip/hip_bf16.h>

// GIN forward: N=10000 nodes, E=80000 edges, per-node feature block [A=2][C=15][D=64]
// All inter-kernel tensors stored bf16; all reductions/BN/pool math in fp32.
// SLICE-MAJOR layout: row r = ac*10000 + n (ac=0..29). BN channel = idx%64 (unchanged).
// LESSONS LEDGER:
//  - R3/R11: do NOT fuse gather with GEMM (W-prologue can't amortize over 30 rows/node).
//  - R13/R15: cooperative BCD fusion refuted: grid.sync() ~65us each on 8-XCD MI355X
//    (device-scope fence across non-coherent L2s) >> the 2 launches + L3 round-trip saved.
//  - R16: slice-major gather — per-slice working set 1.28MB, XCD-partitioned -> L2-resident.
#define N_NODES   10000
#define N_EDGES   80000
#define R_TOTAL   300000
#define ELEMS     19200000   // R_TOTAL*64
#define NODE_F    1920       // 30*64 elements per node
#define N_TILES   18750      // R_TOTAL/16
#define GEMM_GRID 1024       // passA/passB grid
#define BPS       313        // gather blocks per slice (32 nodes/block, 313*32 >= 10000)
#define PD_X      40         // passD blocks per slice (250 nodes each)

typedef __attribute__((ext_vector_type(8))) short short8;   // 8 bf16
typedef __attribute__((ext_vector_type(4))) float f32x4;
typedef __attribute__((ext_vector_type(4))) unsigned int u32x4;
typedef __attribute__((ext_vector_type(2))) unsigned int u32x2;
typedef unsigned short ushort_t;

__device__ __forceinline__ unsigned short f2bf(float f) {
    unsigned u = __builtin_bit_cast(unsigned, f);
    unsigned r = u + 0x7fff + ((u >> 16) & 1);   // RNE
    return (unsigned short)(r >> 16);
}
__device__ __forceinline__ float lo_f(unsigned u) { return __builtin_bit_cast(float, u << 16); }
__device__ __forceinline__ float hi_f(unsigned u) { return __builtin_bit_cast(float, u & 0xffff0000u); }
__device__ __forceinline__ unsigned packbf(float lo, float hi) {
    return ((unsigned)f2bf(hi) << 16) | (unsigned)f2bf(lo);
}

// inline BatchNorm coefficient computation (channel = d in 0..63)
__device__ __forceinline__ void bn_coef(const float* __restrict__ ssum,
                                        const float* __restrict__ ssq,
                                        const float* __restrict__ g,
                                        const float* __restrict__ b, int j,
                                        float& sc, float& sh) {
    const float invM = 1.0f / (float)R_TOTAL;
    float m = ssum[j] * invM;
    float v = ssq[j] * invM - m * m;
    sc = g[j] * rsqrtf(v + 1e-5f);
    sh = b[j] - m * sc;
}

// ---------------- transpose h[a][d][c][n] -> xb[ac][n][d] (bf16, slice-major), + pooled0 ----------------
__global__ __launch_bounds__(256) void k_transpose(const float* __restrict__ h,
                                                   ushort_t* __restrict__ xb,
                                                   float* __restrict__ pooled) {
    __shared__ float tile[64][65];    // [d][nn]
    int tn = blockIdx.x;              // n-tile 0..156
    int ac = blockIdx.y;              // 0..29
    int a = ac / 15, c = ac % 15;
    int t = threadIdx.x;
    int n0 = tn * 64;

    int r = t >> 4, g = t & 15;
    int nbase = n0 + 4 * g;
    const float* hp = h + (size_t)a * 9600000 + (size_t)c * 10000;
#pragma unroll
    for (int it = 0; it < 4; it++) {
        int d = it * 16 + r;
        const float* p = hp + (size_t)d * 150000 + nbase;
        float4 v;
        if (nbase + 3 < N_NODES) {
            v = *(const float4*)p;
        } else {
            v.x = (nbase + 0 < N_NODES) ? p[0] : 0.f;
            v.y = (nbase + 1 < N_NODES) ? p[1] : 0.f;
            v.z = (nbase + 2 < N_NODES) ? p[2] : 0.f;
            v.w = (nbase + 3 < N_NODES) ? p[3] : 0.f;
        }
        tile[d][4 * g + 0] = v.x;
        tile[d][4 * g + 1] = v.y;
        tile[d][4 * g + 2] = v.z;
        tile[d][4 * g + 3] = v.w;
    }
    __syncthreads();

    int nn = t >> 2, dg = (t & 3) * 16;
    int n = n0 + nn;
    if (n < N_NODES) {
        u32x4 oA, oB;
#pragma unroll
        for (int q = 0; q < 4; q++) {
            oA[q] = packbf(tile[dg + 2 * q][nn],     tile[dg + 2 * q + 1][nn]);
            oB[q] = packbf(tile[dg + 8 + 2 * q][nn], tile[dg + 8 + 2 * q + 1][nn]);
        }
        ushort_t* dst = xb + ((size_t)ac * N_NODES + n) * 64 + dg;   // slice-major
        *(u32x4*)dst = oA;
        *(u32x4*)(dst + 8) = oB;
    }

    if (t < 64) {
        float s = 0.f;
        int lim = min(64, N_NODES - n0);
        for (int j = 0; j < lim; j++) s += tile[t][j];
        atomicAdd(&pooled[ac * 64 + t], s);
    }
}

// ---------------- CSR build: degree -> scan -> fill ----------------
__global__ void k_deg(const int* __restrict__ dst, int* __restrict__ deg) {
    int e = blockIdx.x * 256 + threadIdx.x;
    if (e < N_EDGES) atomicAdd(&deg[dst[e]], 1);
}

__global__ __launch_bounds__(256) void k_scan(const int* __restrict__ deg,
                                              int* __restrict__ off,
                                              int* __restrict__ cursor) {
    __shared__ int buf[256];
    int t = threadIdx.x;
    int c0 = t * 40;                 // 256*40 = 10240 >= 10000
    int local[40];
    int s = 0;
    for (int i = 0; i < 40; i++) {
        int idx = c0 + i;
        int d = (idx < N_NODES) ? deg[idx] : 0;
        local[i] = d;
        s += d;
    }
    buf[t] = s;
    __syncthreads();
    for (int st = 1; st < 256; st <<= 1) {
        int v = (t >= st) ? buf[t - st] : 0;
        __syncthreads();
        buf[t] += v;
        __syncthreads();
    }
    int run = buf[t] - s;
    for (int i = 0; i < 40; i++) {
        int idx = c0 + i;
        if (idx < N_NODES) {
            off[idx] = run;
            cursor[idx] = run;
            run += local[i];
        }
    }
    if (t == 255) off[N_NODES] = buf[255];
}

__global__ void k_fill(const int* __restrict__ src, const int* __restrict__ dst,
                       int* __restrict__ cursor, int* __restrict__ csr) {
    int e = blockIdx.x * 256 + threadIdx.x;
    if (e < N_EDGES) {
        int p = atomicAdd(&cursor[dst[e]], 1);
        csr[p] = src[e];
    }
}

// ---------------- gather (slice-major, XCD-partitioned) ----------------
// agg[ac][n] = sum_{e in in(n)} x[ac][src_e].  Per-slice working set = 1.28MB -> one XCD's L2.
// bid&7 selects XCD (HW round-robin mapping); each XCD owns 3-4 slices processed in order.
__global__ __launch_bounds__(256) void k_gather(const ushort_t* __restrict__ xs,
                                                ushort_t* __restrict__ aggs,
                                                const int* __restrict__ off,
                                                const int* __restrict__ csr) {
    int bid = blockIdx.x;
    int xcd = bid & 7, k = bid >> 3;
    int base = (xcd < 6) ? xcd * 4 : 24 + (xcd - 6) * 3;   // slices per XCD: 4,4,4,4,4,4,3,3
    int nsl  = (xcd < 6) ? 4 : 3;
    int si = k / BPS;
    if (si >= nsl) return;
    int ac = base + si;
    int ng = k - si * BPS;
    int t = threadIdx.x;
    int nl = t >> 3, c8 = t & 7;       // 32 nodes/block, 8 threads/node (16B chunk each)
    int n = ng * 32 + nl;
    if (n >= N_NODES) return;

    const ushort_t* xsl = xs + (size_t)ac * N_NODES * 64;
    float acc[8] = {0.f, 0.f, 0.f, 0.f, 0.f, 0.f, 0.f, 0.f};
    int e0 = off[n], e1 = off[n + 1];
    int i = e0;
    for (; i + 4 <= e1; i += 4) {
        int s0 = csr[i], s1 = csr[i + 1], s2 = csr[i + 2], s3 = csr[i + 3];
        u32x4 v0 = *(const u32x4*)(xsl + (size_t)s0 * 64 + c8 * 8);
        u32x4 v1 = *(const u32x4*)(xsl + (size_t)s1 * 64 + c8 * 8);
        u32x4 v2 = *(const u32x4*)(xsl + (size_t)s2 * 64 + c8 * 8);
        u32x4 v3 = *(const u32x4*)(xsl + (size_t)s3 * 64 + c8 * 8);
#pragma unroll
        for (int q = 0; q < 4; q++) {
            acc[2 * q]     += (lo_f(v0[q]) + lo_f(v1[q])) + (lo_f(v2[q]) + lo_f(v3[q]));
            acc[2 * q + 1] += (hi_f(v0[q]) + hi_f(v1[q])) + (hi_f(v2[q]) + hi_f(v3[q]));
        }
    }
    for (; i < e1; i++) {
        int s0 = csr[i];
        u32x4 v = *(const u32x4*)(xsl + (size_t)s0 * 64 + c8 * 8);
#pragma unroll
        for (int q = 0; q < 4; q++) {
            acc[2 * q]     += lo_f(v[q]);
            acc[2 * q + 1] += hi_f(v[q]);
        }
    }
    u32x4 o;
#pragma unroll
    for (int q = 0; q < 4; q++) o[q] = packbf(acc[2 * q], acc[2 * q + 1]);
    *(u32x4*)(aggs + ((size_t)ac * N_NODES + n) * 64 + c8 * 8) = o;
}

// ---------------- passA (MFMA): to = ((1+eps)*x + agg) @ W0 + b0 ; stats(to) ----------------
// Rows are (ac,n) in slice-major order; kernel is row-order-agnostic.
__global__ __launch_bounds__(256) void k_passA(const ushort_t* __restrict__ xb,
                                               const ushort_t* __restrict__ aggb,
                                               ushort_t* __restrict__ to,
                                               const float* __restrict__ W,
                                               const float* __restrict__ bias,
                                               const float* __restrict__ epsp, int l,
                                               float* __restrict__ ssum, float* __restrict__ ssq) {
    int tid = threadIdx.x;
    int lane = tid & 63, wid = tid >> 6;
    int m = lane & 15, kg = lane >> 4;

    short8 bfr[2][4];                 // [kstep][nt] ; col = 4m+nt
#pragma unroll
    for (int s = 0; s < 2; s++)
#pragma unroll
        for (int nt = 0; nt < 4; nt++) {
            short8 v;
#pragma unroll
            for (int j = 0; j < 8; j++)
                v[j] = (short)f2bf(W[(s * 32 + kg * 8 + j) * 64 + 4 * m + nt]);
            bfr[s][nt] = v;
        }
    float bcol[4];
#pragma unroll
    for (int nt = 0; nt < 4; nt++) bcol[nt] = bias[4 * m + nt];
    float e1 = 1.0f + epsp[l];

    float s0a[4] = {0.f, 0.f, 0.f, 0.f}, s1a[4] = {0.f, 0.f, 0.f, 0.f};

    for (int tile = blockIdx.x * 4 + wid; tile < N_TILES; tile += gridDim.x * 4) {
        size_t row0 = (size_t)tile * 16;
        const u32x4* xr = (const u32x4*)(xb + (row0 + m) * 64);
        const u32x4* ar = (const u32x4*)(aggb + (row0 + m) * 64);
        short8 afr[2];
#pragma unroll
        for (int s = 0; s < 2; s++) {
            u32x4 xv = xr[s * 4 + kg];
            u32x4 av = ar[s * 4 + kg];
            u32x4 zv;
#pragma unroll
            for (int q = 0; q < 4; q++) {
                float zl = fmaf(e1, lo_f(xv[q]), lo_f(av[q]));
                float zh = fmaf(e1, hi_f(xv[q]), hi_f(av[q]));
                zv[q] = packbf(zl, zh);
            }
            afr[s] = __builtin_bit_cast(short8, zv);
        }
        f32x4 acc0 = {0,0,0,0}, acc1 = {0,0,0,0}, acc2 = {0,0,0,0}, acc3 = {0,0,0,0};
#pragma unroll
        for (int s = 0; s < 2; s++) {
            acc0 = __builtin_amdgcn_mfma_f32_16x16x32_bf16(afr[s], bfr[s][0], acc0, 0, 0, 0);
            acc1 = __builtin_amdgcn_mfma_f32_16x16x32_bf16(afr[s], bfr[s][1], acc1, 0, 0, 0);
            acc2 = __builtin_amdgcn_mfma_f32_16x16x32_bf16(afr[s], bfr[s][2], acc2, 0, 0, 0);
            acc3 = __builtin_amdgcn_mfma_f32_16x16x32_bf16(afr[s], bfr[s][3], acc3, 0, 0, 0);
        }
        ushort_t* tw = to + (row0 + kg * 4) * 64 + 4 * m;
#pragma unroll
        for (int r = 0; r < 4; r++) {
            float v0 = acc0[r] + bcol[0];
            float v1 = acc1[r] + bcol[1];
            float v2 = acc2[r] + bcol[2];
            float v3 = acc3[r] + bcol[3];
            u32x2 pk;
            pk[0] = packbf(v0, v1);
            pk[1] = packbf(v2, v3);
            *(u32x2*)(tw + (size_t)r * 64) = pk;
            s0a[0] += v0; s1a[0] += v0 * v0;
            s0a[1] += v1; s1a[1] += v1 * v1;
            s0a[2] += v2; s1a[2] += v2 * v2;
            s0a[3] += v3; s1a[3] += v3 * v3;
        }
    }
    __shared__ float shs0[64], shs1[64];
    if (tid < 64) { shs0[tid] = 0.f; shs1[tid] = 0.f; }
    __syncthreads();
#pragma unroll
    for (int nt = 0; nt < 4; nt++) {
        atomicAdd(&shs0[4 * m + nt], s0a[nt]);
        atomicAdd(&shs1[4 * m + nt], s1a[nt]);
    }
    __syncthreads();
    if (tid < 64) {
        atomicAdd(&ssum[tid], shs0[tid]);
        atomicAdd(&ssq[tid], shs1[tid]);
    }
}

// ---------------- passB (MFMA): to = relu(bn0(ti)) @ W1 + b1 ; stats(to) ----------------
__global__ __launch_bounds__(256) void k_passB(const ushort_t* __restrict__ ti,
                                               ushort_t* __restrict__ to,
                                               const float* __restrict__ W,
                                               const float* __restrict__ bias,
                                               const float* __restrict__ ssum0,
                                               const float* __restrict__ ssq0,
                                               const float* __restrict__ g0,
                                               const float* __restrict__ be0,
                                               float* __restrict__ ssum, float* __restrict__ ssq) {
    int tid = threadIdx.x;
    int lane = tid & 63, wid = tid >> 6;
    int m = lane & 15, kg = lane >> 4;

    short8 bfr[2][4];                 // col = 4m+nt
#pragma unroll
    for (int s = 0; s < 2; s++)
#pragma unroll
        for (int nt = 0; nt < 4; nt++) {
            short8 v;
#pragma unroll
            for (int j = 0; j < 8; j++)
                v[j] = (short)f2bf(W[(s * 32 + kg * 8 + j) * 64 + 4 * m + nt]);
            bfr[s][nt] = v;
        }
    float bcol[4];
#pragma unroll
    for (int nt = 0; nt < 4; nt++) bcol[nt] = bias[4 * m + nt];
    float scv[2][8], shv[2][8];       // BN for input channels k = s*32+kg*8+j
#pragma unroll
    for (int s = 0; s < 2; s++)
#pragma unroll
        for (int j = 0; j < 8; j++)
            bn_coef(ssum0, ssq0, g0, be0, s * 32 + kg * 8 + j, scv[s][j], shv[s][j]);

    float s0a[4] = {0.f, 0.f, 0.f, 0.f}, s1a[4] = {0.f, 0.f, 0.f, 0.f};

    for (int tile = blockIdx.x * 4 + wid; tile < N_TILES; tile += gridDim.x * 4) {
        size_t row0 = (size_t)tile * 16;
        const u32x4* tr = (const u32x4*)(ti + (row0 + m) * 64);
        short8 afr[2];
#pragma unroll
        for (int s = 0; s < 2; s++) {
            u32x4 tv = tr[s * 4 + kg];
            u32x4 zv;
#pragma unroll
            for (int q = 0; q < 4; q++) {
                float zl_ = fmaxf(fmaf(lo_f(tv[q]), scv[s][2 * q],     shv[s][2 * q]),     0.f);
                float zh_ = fmaxf(fmaf(hi_f(tv[q]), scv[s][2 * q + 1], shv[s][2 * q + 1]), 0.f);
                zv[q] = packbf(zl_, zh_);
            }
            afr[s] = __builtin_bit_cast(short8, zv);
        }
        f32x4 acc0 = {0,0,0,0}, acc1 = {0,0,0,0}, acc2 = {0,0,0,0}, acc3 = {0,0,0,0};
#pragma unroll
        for (int s = 0; s < 2; s++) {
            acc0 = __builtin_amdgcn_mfma_f32_16x16x32_bf16(afr[s], bfr[s][0], acc0, 0, 0, 0);
            acc1 = __builtin_amdgcn_mfma_f32_16x16x32_bf16(afr[s], bfr[s][1], acc1, 0, 0, 0);
            acc2 = __builtin_amdgcn_mfma_f32_16x16x32_bf16(afr[s], bfr[s][2], acc2, 0, 0, 0);
            acc3 = __builtin_amdgcn_mfma_f32_16x16x32_bf16(afr[s], bfr[s][3], acc3, 0, 0, 0);
        }
        ushort_t* tw = to + (row0 + kg * 4) * 64 + 4 * m;
#pragma unroll
        for (int r = 0; r < 4; r++) {
            float v0 = acc0[r] + bcol[0];
            float v1 = acc1[r] + bcol[1];
            float v2 = acc2[r] + bcol[2];
            float v3 = acc3[r] + bcol[3];
            u32x2 pk;
            pk[0] = packbf(v0, v1);
            pk[1] = packbf(v2, v3);
            *(u32x2*)(tw + (size_t)r * 64) = pk;
            s0a[0] += v0; s1a[0] += v0 * v0;
            s0a[1] += v1; s1a[1] += v1 * v1;
            s0a[2] += v2; s1a[2] += v2 * v2;
            s0a[3] += v3; s1a[3] += v3 * v3;
        }
    }
    __shared__ float shs0[64], shs1[64];
    if (tid < 64) { shs0[tid] = 0.f; shs1[tid] = 0.f; }
    __syncthreads();
#pragma unroll
    for (int nt = 0; nt < 4; nt++) {
        atomicAdd(&shs0[4 * m + nt], s0a[nt]);
        atomicAdd(&shs1[4 * m + nt], s1a[nt]);
    }
    __syncthreads();
    if (tid < 64) {
        atomicAdd(&ssum[tid], shs0[tid]);
        atomicAdd(&ssq[tid], shs1[tid]);
    }
}

// ---------------- statsC: stats of u = relu(bn_a(t3)), read-only bf16 ----------------
__global__ __launch_bounds__(256) void k_statsC(const ushort_t* __restrict__ tb,
                                                const float* __restrict__ ssum1,
                                                const float* __restrict__ ssq1,
                                                const float* __restrict__ ga,
                                                const float* __restrict__ ba,
                                                float* __restrict__ ssum2,
                                                float* __restrict__ ssq2) {
    __shared__ float shs0[64], shs1[64];
    int tid = threadIdx.x;
    if (tid < 64) { shs0[tid] = 0.f; shs1[tid] = 0.f; }
    __syncthreads();
    int ch0 = (tid & 7) * 8;          // chunk-in-row = tid%8 (stride is multiple of 8)
    float sc[8], sh[8];
#pragma unroll
    for (int j = 0; j < 8; j++) bn_coef(ssum1, ssq1, ga, ba, ch0 + j, sc[j], sh[j]);
    float s0[8] = {0,0,0,0,0,0,0,0}, s1[8] = {0,0,0,0,0,0,0,0};
    const u32x4* t4 = (const u32x4*)tb;
    const int total = ELEMS / 8;
    int stride = gridDim.x * 256;
    for (int i = blockIdx.x * 256 + tid; i < total; i += stride) {
        u32x4 v = t4[i];
#pragma unroll
        for (int q = 0; q < 4; q++) {
            float e;
            e = fmaxf(fmaf(lo_f(v[q]), sc[2 * q],     sh[2 * q]),     0.f);
            s0[2 * q] += e;     s1[2 * q] += e * e;
            e = fmaxf(fmaf(hi_f(v[q]), sc[2 * q + 1], sh[2 * q + 1]), 0.f);
            s0[2 * q + 1] += e; s1[2 * q + 1] += e * e;
        }
    }
#pragma unroll
    for (int j = 0; j < 8; j++) {
        atomicAdd(&shs0[ch0 + j], s0[j]);
        atomicAdd(&shs1[ch0 + j], s1[j]);
    }
    __syncthreads();
    if (tid < 64) {
        atomicAdd(&ssum2[tid], shs0[tid]);
        atomicAdd(&ssq2[tid], shs1[tid]);
    }
}

// ---------------- passD (slice-major): grid (PD_X, 30) ----------------
// Block (bx, ac): nodes [bx*250, bx*250+250) of slice ac. Pool channel = ac*64 + d (fixed/thread).
__global__ __launch_bounds__(256) void k_passD(const ushort_t* __restrict__ tb,
                                               ushort_t* __restrict__ xb,
                                               const float* __restrict__ ssum1,
                                               const float* __restrict__ ssq1,
                                               const float* __restrict__ ga,
                                               const float* __restrict__ ba,
                                               const float* __restrict__ ssum2,
                                               const float* __restrict__ ssq2,
                                               const float* __restrict__ go,
                                               const float* __restrict__ bo,
                                               float* __restrict__ pp,   // [30*PD_X][64]
                                               int writeX) {
    __shared__ float pl[64];
    int t = threadIdx.x;
    int nl = t >> 3, c8 = t & 7;
    int ac = blockIdx.y, bx = blockIdx.x;
    int ch0 = c8 * 8;                 // BN channel base (d only)
    float sc1[8], sh1[8], sc2[8], sh2[8];
#pragma unroll
    for (int j = 0; j < 8; j++) {
        bn_coef(ssum1, ssq1, ga, ba, ch0 + j, sc1[j], sh1[j]);
        bn_coef(ssum2, ssq2, go, bo, ch0 + j, sc2[j], sh2[j]);
    }
    if (t < 64) pl[t] = 0.f;
    __syncthreads();

    float pool[8] = {0,0,0,0,0,0,0,0};
    int n0 = bx * 250;
    for (int n = n0 + nl; n < n0 + 250; n += 32) {
        size_t r = (size_t)ac * N_NODES + n;
        u32x4 v = *(const u32x4*)(tb + r * 64 + ch0);
        u32x4 o;
#pragma unroll
        for (int q = 0; q < 4; q++) {
            float el = fmaxf(fmaf(fmaxf(fmaf(lo_f(v[q]), sc1[2 * q], sh1[2 * q]), 0.f),
                                  sc2[2 * q], sh2[2 * q]), 0.f);
            float eh = fmaxf(fmaf(fmaxf(fmaf(hi_f(v[q]), sc1[2 * q + 1], sh1[2 * q + 1]), 0.f),
                                  sc2[2 * q + 1], sh2[2 * q + 1]), 0.f);
            pool[2 * q] += el;
            pool[2 * q + 1] += eh;
            o[q] = packbf(el, eh);
        }
        if (writeX) *(u32x4*)(xb + r * 64 + ch0) = o;
    }
#pragma unroll
    for (int j = 0; j < 8; j++) atomicAdd(&pl[ch0 + j], pool[j]);
    __syncthreads();
    if (t < 64) pp[((size_t)ac * PD_X + bx) * 64 + t] = pl[t];
}

// ---------------- redpool: pooled[(z+1)][ch] = sum over PD_X partials; grid (8,1,2) ----------------
__global__ __launch_bounds__(256) void k_redpool(const float* __restrict__ pp0,
                                                 const float* __restrict__ pp1,
                                                 float* __restrict__ pooled) {
    int ch = blockIdx.x * 256 + threadIdx.x;
    if (ch >= NODE_F) return;
    const float* pp = (blockIdx.z == 0) ? pp0 : pp1;
    int ac = ch >> 6, d = ch & 63;
    float a = 0.f;
    for (int b = 0; b < PD_X; b++) a += pp[((size_t)ac * PD_X + b) * 64 + d];
    pooled[(blockIdx.z + 1) * NODE_F + ch] = a;
}

// ---------------- final readout: score + fc -> out[2] ----------------
__global__ void k_final(const float* __restrict__ pooled,   // [3][1920]
                        const float* __restrict__ Wp,       // [3][64][10]
                        const float* __restrict__ bp,       // [3][10]
                        const float* __restrict__ Wfc,      // [15][10]
                        const float* __restrict__ bfc, float* __restrict__ out) {
    __shared__ float oa[2];
    int t = threadIdx.x;
    if (t < 2) oa[t] = 0.f;
    __syncthreads();
    if (t < 300) {
        int a = t / 150, rem = t % 150, c = rem / 10, hh = rem % 10;
        int ac = a * 15 + c;
        float sc_sum = 0.f;
        for (int i = 0; i < 3; i++) {
            float s = bp[i * 10 + hh];
            const float* pp = pooled + i * NODE_F + ac * 64;
            const float* wp = Wp + i * 640 + hh;
            for (int d = 0; d < 64; d++) s += pp[d] * wp[d * 10];
            sc_sum += s;
        }
        atomicAdd(&oa[a], sc_sum * Wfc[c * 10 + hh]);
    }
    __syncthreads();
    if (t < 2) out[t] = oa[t] + bfc[0];
}

extern "C" void kernel_launch(void* const* d_in, const int* in_sizes, int n_in,
                              void* d_out, int out_size, void* d_ws, size_t ws_size,
                              hipStream_t stream) {
    const float* h   = (const float*)d_in[0];
    const float* eps = (const float*)d_in[1];
    const float* W0  = (const float*)d_in[2];
    const float* b0  = (const float*)d_in[3];
    const float* g0  = (const float*)d_in[4];
    const float* be0 = (const float*)d_in[5];
    const float* W1  = (const float*)d_in[6];
    const float* b1  = (const float*)d_in[7];
    const float* ga  = (const float*)d_in[8];
    const float* ba  = (const float*)d_in[9];
    const float* go  = (const float*)d_in[10];
    const float* bo  = (const float*)d_in[11];
    const float* Wp  = (const float*)d_in[12];
    const float* bp  = (const float*)d_in[13];
    const float* Wfc = (const float*)d_in[14];
    const float* bfc = (const float*)d_in[15];
    const int*   src = (const int*)d_in[16];
    const int*   dst = (const int*)d_in[17];
    float* out = (float*)d_out;

    ushort_t* xb   = (ushort_t*)d_ws;            // [ELEMS] bf16 (node features, slice-major)
    ushort_t* bufP = xb + ELEMS;                 // [ELEMS] bf16 (agg / t3)
    ushort_t* bufQ = bufP + ELEMS;               // [ELEMS] bf16 (t1)
    float* small   = (float*)(bufQ + ELEMS);
    float* bn = small;                           // 6 x [sum64|sq64] padded to 256
    float* pooled = small + 6 * 256;             // [3][1920]
    int* ideg = (int*)(pooled + 3 * NODE_F);     // [10000]
    int* ioff = ideg + N_NODES;                  // [10001]
    int* icur = ioff + N_NODES + 1;              // [10000]
    int* icsr = icur + N_NODES;                  // [80000]
    float* pp0 = (float*)(icsr + N_EDGES);       // [30*PD_X][64] layer-1 pool partials
    float* pp1 = pp0 + 30 * PD_X * 64;           // [30*PD_X][64] layer-2 pool partials

    hipMemsetAsync(small, 0,
                   (6 * 256 + 3 * NODE_F) * sizeof(float) + N_NODES * sizeof(int), stream);

    k_deg<<<(N_EDGES + 255) / 256, 256, 0, stream>>>(dst, ideg);
    k_scan<<<1, 256, 0, stream>>>(ideg, ioff, icur);
    k_fill<<<(N_EDGES + 255) / 256, 256, 0, stream>>>(src, dst, icur, icsr);

    k_transpose<<<dim3(157, 30), 256, 0, stream>>>(h, xb, pooled);

    for (int l = 0; l < 2; l++) {
        float* s0s = bn + l * 3 * 256;
        float* s1s = s0s + 256;
        float* s2s = s1s + 256;
        float* ppl = (l == 0) ? pp0 : pp1;
        k_gather<<<8 * 4 * BPS, 256, 0, stream>>>(xb, bufP, ioff, icsr);
        k_passA<<<GEMM_GRID, 256, 0, stream>>>(xb, bufP, bufQ,
                                               W0 + l * 4096, b0 + l * 64, eps, l,
                                               s0s, s0s + 64);
        k_passB<<<GEMM_GRID, 256, 0, stream>>>(bufQ, bufP, W1 + l * 4096, b1 + l * 64,
                                               s0s, s0s + 64, g0 + l * 64, be0 + l * 64,
                                               s1s, s1s + 64);
        k_statsC<<<1024, 256, 0, stream>>>(bufP, s1s, s1s + 64, ga + l * 64, ba + l * 64,
                                           s2s, s2s + 64);
        k_passD<<<dim3(PD_X, 30), 256, 0, stream>>>(bufP, xb, s1s, s1s + 64,
                                                    ga + l * 64, ba + l * 64,
                                                    s2s, s2s + 64, go + l * 64, bo + l * 64,
                                                    ppl, (l == 0) ? 1 : 0);
    }
    k_redpool<<<dim3(8, 1, 2), 256, 0, stream>>>(pp0, pp1, pooled);
    k_final<<<1, 320, 0, stream>>>(pooled, Wp, bp, Wfc, bfc, out);
}